// Round 20
// baseline (5323.399 us; speedup 1.0000x reference)
//
#include <hip/hip_runtime.h>

#define B_ 4
#define T_ 1024
#define C_ 768
#define H_ 12
#define E_ 4
#define L_ 2
#define DH_ 64
#define M_ (B_*T_)   // 4096
#define QKVS_ (3*C_) // 2304, fused QKV row stride
#define LOG2E_ 1.4426950408889634f

typedef __attribute__((ext_vector_type(8))) short bf16x8;
typedef __attribute__((ext_vector_type(4))) float f32x4;

__device__ __forceinline__ unsigned short f2bf(float f) {
  unsigned int u = __float_as_uint(f);
  unsigned int r = (u + 0x7FFFu + ((u >> 16) & 1u)) >> 16;
  return (unsigned short)r;
}
__device__ __forceinline__ float bf2f(unsigned short s) {
  return __uint_as_float(((unsigned int)s) << 16);
}
// pack 2 f32 -> 2 bf16 in one u32, RNE
__device__ __forceinline__ unsigned int cvt_pk_bf16(float lo, float hi) {
  unsigned int r;
  asm("v_cvt_pk_bf16_f32 %0, %1, %2" : "=v"(r) : "v"(lo), "v"(hi));
  return r;
}
// single-instruction exp2 via COMPILER intrinsic (hazards modeled; R16 lesson)
__device__ __forceinline__ float fexp2(float x) {
#if __has_builtin(__builtin_amdgcn_exp2f)
  return __builtin_amdgcn_exp2f(x);
#else
  return exp2f(x);
#endif
}

typedef __attribute__((address_space(1))) unsigned int gu32;
typedef __attribute__((address_space(3))) unsigned int lu32;
__device__ __forceinline__ void gld_lds16(const void* g, void* l) {
  __builtin_amdgcn_global_load_lds((gu32*)g, (lu32*)l, 16, 0, 0);
}

// gelu(x) = x * sigmoid(2u)
__device__ __forceinline__ float gelu_fast(float x) {
  float u = 0.7978845608028654f * x * (1.0f + 0.044715f * x * x);
  float d = 1.0f + fexp2(-2.8853900817779268f * u);
  return x * __builtin_amdgcn_rcpf(d);
}

// ---------------- 256x256 batched GEMM: 2-slot ring, 2 BLOCKS/CU --------------
// LDS cut 128->64 KiB (ring of 2 K-half slots per matrix) so TWO blocks fit per
// CU -> 4 waves/SIMD. Mechanism: cross-block TLP covers barrier/LDS stalls that
// six intra-wave schedule variants (R7..R19) could not — occupancy was pinned
// at 1 block/CU (21%) the whole time.
// Per K-half m: {12 ds_read frags (slot m&1); 32 MFMA; barrier1 (all waves'
// reads retired: per-wave lgkm-before-MFMA + barrier); stage kh m+2 -> slot
// m&1; counted vmcnt (4 steady / 0 tail); barrier2}.
template <int ACT>
__global__ __launch_bounds__(512, 4) void gemm256(
    const unsigned short* __restrict__ A, const unsigned short* __restrict__ Bt,
    const float* __restrict__ bias, unsigned short* __restrict__ D,
    int M, int N, int K, long long sA, long long sB, long long sBias, long long sD,
    float bscale)
{
  __shared__ unsigned short shA[2][256*32];
  __shared__ unsigned short shB[2][256*32];
  const int tid = threadIdx.x;
  const int lane = tid & 63, wid = tid >> 6;
  const int l15 = lane & 15, lhi = lane >> 4;
  const int wm = wid >> 2, wn = wid & 3;        // 2 x 4 wave grid

  // T1: XCD-aware block swizzle (bijective: nwg % 8 == 0 for all our grids)
  const int gx = gridDim.x, gxy = gx * gridDim.y;
  const int nwg = gxy * gridDim.z;
  int flat = blockIdx.z*gxy + blockIdx.y*gx + blockIdx.x;
  flat = (flat & 7) * (nwg >> 3) + (flat >> 3);
  const int g = flat / gxy;
  const int rem = flat - g*gxy;
  const int by = rem / gx, bx = rem - by*gx;
  const int m0 = by * 256, n0 = bx * 256;

  const unsigned short* Ab = A + (size_t)g * sA;
  const unsigned short* Bb = Bt + (size_t)g * sB;
  const float* biasb = bias + (size_t)g * sBias;
  unsigned short* Db = D + (size_t)g * sD;

  f32x4 acc[8][4] = {};

  const int l15h = l15 >> 1;
  const int s8 = (((((l15 & 1) << 2) | lhi) ^ (l15h & 7)) << 3);
  const int arp = wm*64;   // + mh*32 + i*8 + l15h
  const int brp = wn*32;   // + nf*8 + l15h

  auto stageA = [&](int slot, int kh) {
    const int kb = kh << 5;
    #pragma unroll
    for (int iss = 0; iss < 2; ++iss) {
      const int c = tid + iss*512;
      const int q = c >> 3, pp = (c & 7) ^ (q & 7);
      gld_lds16(Ab + (size_t)(m0 + (q << 1) + (pp >> 2))*K + kb + ((pp & 3) << 3),
                &shA[slot][c*8]);
    }
  };
  auto stageB = [&](int slot, int kh) {
    const int kb = kh << 5;
    #pragma unroll
    for (int iss = 0; iss < 2; ++iss) {
      const int c = tid + iss*512;
      const int q = c >> 3, pp = (c & 7) ^ (q & 7);
      gld_lds16(Bb + (size_t)(n0 + (q << 1) + (pp >> 2))*K + kb + ((pp & 3) << 3),
                &shB[slot][c*8]);
    }
  };

  const int nkt = K >> 6;
  const int nkh = nkt << 1;      // even; >= 6 for all our shapes

  // prologue: stage kh 0,1; vmcnt(4) confirms kh0 (kh1's 4 in flight)
  stageA(0, 0); stageB(0, 0);
  stageA(1, 1); stageB(1, 1);
  asm volatile("s_waitcnt vmcnt(4)" ::: "memory");
  __builtin_amdgcn_s_barrier();

  for (int m = 0; m < nkh; ++m) {
    const int slot = m & 1;
    bf16x8 bfr[4], af0[4], af1[4];
    #pragma unroll
    for (int nf = 0; nf < 4; ++nf)
      bfr[nf] = *(const bf16x8*)&shB[slot][(brp + nf*8 + l15h)*64 + s8];
    #pragma unroll
    for (int i = 0; i < 4; ++i)
      af0[i] = *(const bf16x8*)&shA[slot][(arp + i*8 + l15h)*64 + s8];
    #pragma unroll
    for (int i = 0; i < 4; ++i)
      af1[i] = *(const bf16x8*)&shA[slot][(arp + 32 + i*8 + l15h)*64 + s8];
    __builtin_amdgcn_s_setprio(1);
    #pragma unroll
    for (int i = 0; i < 4; ++i)
      #pragma unroll
      for (int nf = 0; nf < 4; ++nf)
        acc[i][nf] = __builtin_amdgcn_mfma_f32_16x16x32_bf16(
            af0[i], bfr[nf], acc[i][nf], 0, 0, 0);
    #pragma unroll
    for (int i = 0; i < 4; ++i)
      #pragma unroll
      for (int nf = 0; nf < 4; ++nf)
        acc[4+i][nf] = __builtin_amdgcn_mfma_f32_16x16x32_bf16(
            af1[i], bfr[nf], acc[4+i][nf], 0, 0, 0);
    __builtin_amdgcn_s_setprio(0);
    __builtin_amdgcn_s_barrier();            // all waves' reads of this slot retired
    const int mst = m + 2;
    if (mst < nkh) { stageA(slot, mst); stageB(slot, mst); }
    if (m + 1 < nkh) {
      if (mst < nkh) asm volatile("s_waitcnt vmcnt(4)" ::: "memory"); // confirms kh m+1
      else           asm volatile("s_waitcnt vmcnt(0)" ::: "memory");
      __builtin_amdgcn_s_barrier();
    }
  }

  // ---- LDS-staged coalesced C-write (fully unrolled: static acc indexing) ----
  unsigned short* cbuf = (unsigned short*)&shA[0][0];
  const int lr = tid >> 4, ckk = tid & 15;
  const int growb = m0 + ((lr >> 4) ? 128 : 0) + (lr & 15);
  #pragma unroll
  for (int mf = 0; mf < 8; ++mf) {
    __builtin_amdgcn_s_barrier();
    #pragma unroll
    for (int nf = 0; nf < 4; ++nf) {
      const int col = wn*64 + nf*16 + l15;
      const float bv = bscale * biasb[n0 + col];
      #pragma unroll
      for (int r = 0; r < 4; ++r) {
        float v = acc[mf][nf][r] + bv;
        if (ACT == 1) v = gelu_fast(v);
        cbuf[(wm*16 + lhi*4 + r)*264 + col] = f2bf(v);
      }
    }
    __builtin_amdgcn_s_barrier();
    const size_t growN = (size_t)(growb + mf*16) * N + n0;
    #pragma unroll
    for (int cc2 = 0; cc2 < 2; ++cc2) {
      const int c = ckk + cc2*16;
      uint4 v = *(const uint4*)&cbuf[lr*264 + c*8];
      *(uint4*)&Db[growN + c*8] = v;
    }
  }
}

// ---------------- flash attention: QBLK=128 (8 waves), swapped-QK^T, no-max ----
__global__ __launch_bounds__(512) void flash_attn(
    const unsigned short* __restrict__ qkv, const unsigned short* __restrict__ vt,
    unsigned short* __restrict__ o)
{
  __shared__ unsigned short shK[2][64*64];
  __shared__ unsigned short shV[2][64*64];   // V^T tile: [d][t]
  __shared__ unsigned short shP[8][16*64];
  const int tid = threadIdx.x;
  const int wid = tid >> 6, lane = tid & 63;
  const int l15 = lane & 15, lhi = lane >> 4;
  const int qt = blockIdx.x, h = blockIdx.y, eb = blockIdx.z;

  const unsigned short* qrow = qkv + ((size_t)eb*T_ + qt*128 + wid*16 + l15) * QKVS_ + h*DH_;
  bf16x8 aq0 = *(const bf16x8*)(qrow + lhi*8);
  bf16x8 aq1 = *(const bf16x8*)(qrow + 32 + lhi*8);

  f32x4 oacc[4] = {};
  float lpart = 0.f;   // per-lane partial denominator, qrow = l15

  const int krow = tid >> 3;                               // 0..63 (512 threads)
  const int swzsrc = (((tid & 7) ^ (krow & 7)) << 3);
  const unsigned short* kbase = qkv + (size_t)eb*T_*QKVS_ + C_ + h*DH_;
  const unsigned short* vbase = vt + ((size_t)eb*H_ + h)*DH_*T_;

  auto stage = [&](int buf, int kt) {
    gld_lds16(kbase + (size_t)(kt*64 + krow)*QKVS_ + swzsrc, &shK[buf][tid*8]);
    gld_lds16(vbase + (size_t)krow*T_ + kt*64 + swzsrc,      &shV[buf][tid*8]);
  };

  stage(0, 0);
  __syncthreads();
  int cur = 0;
  const int swzr = l15 & 7;
  const int c0 = (lhi ^ swzr) << 3;
  const int c1 = ((4 + lhi) ^ swzr) << 3;
  const int pwbase = l15*64 + ((lhi & 1) << 2);
  const int pwh = lhi >> 1;

  for (int kt = 0; kt < T_/64; ++kt) {
    if (kt + 1 < T_/64) stage(cur ^ 1, kt + 1);

    f32x4 s[4];
    #pragma unroll
    for (int kb = 0; kb < 4; ++kb) {
      const int row = (kb*16 + l15)*64;
      bf16x8 bk0 = *(const bf16x8*)&shK[cur][row + c0];
      bf16x8 bk1 = *(const bf16x8*)&shK[cur][row + c1];
      f32x4 z = {};
      z = __builtin_amdgcn_mfma_f32_16x16x32_bf16(bk0, aq0, z, 0, 0, 0);       // swapped
      s[kb] = __builtin_amdgcn_mfma_f32_16x16x32_bf16(bk1, aq1, z, 0, 0, 0);
    }
    unsigned int pk0[4], pk1[4];
    #pragma unroll
    for (int kb = 0; kb < 4; ++kb) {
      #pragma unroll
      for (int r = 0; r < 4; ++r) {
        float pv = fexp2(s[kb][r]);
        s[kb][r] = pv;
        lpart += pv;
      }
      pk0[kb] = cvt_pk_bf16(s[kb][0], s[kb][1]);
      pk1[kb] = cvt_pk_bf16(s[kb][2], s[kb][3]);
    }
    #pragma unroll
    for (int kb = 0; kb < 4; ++kb) {
      const int chunk = (2*kb + pwh) ^ swzr;
      uint2 w = {pk0[kb], pk1[kb]};
      *(uint2*)&shP[wid][pwbase + chunk*8] = w;
    }
    bf16x8 pa0 = *(const bf16x8*)&shP[wid][l15*64 + c0];
    bf16x8 pa1 = *(const bf16x8*)&shP[wid][l15*64 + c1];
    #pragma unroll
    for (int n = 0; n < 4; ++n) {
      const int row = (n*16 + l15)*64;
      bf16x8 bv0 = *(const bf16x8*)&shV[cur][row + c0];
      bf16x8 bv1 = *(const bf16x8*)&shV[cur][row + c1];
      oacc[n] = __builtin_amdgcn_mfma_f32_16x16x32_bf16(pa0, bv0, oacc[n], 0, 0, 0);
      oacc[n] = __builtin_amdgcn_mfma_f32_16x16x32_bf16(pa1, bv1, oacc[n], 0, 0, 0);
    }
    __syncthreads();
    cur ^= 1;
  }
  lpart += __shfl_xor(lpart, 16);
  lpart += __shfl_xor(lpart, 32);
  float li[4];
  #pragma unroll
  for (int r = 0; r < 4; ++r) li[r] = __shfl(lpart, lhi*4 + r);
  #pragma unroll
  for (int n = 0; n < 4; ++n)
    #pragma unroll
    for (int r = 0; r < 4; ++r) {
      float v = oacc[n][r] / li[r];
      o[((size_t)eb*T_ + qt*128 + wid*16 + lhi*4 + r) * C_ + h*DH_ + n*16 + l15] = f2bf(v);
    }
}

// ---------------- transpose+cast: out[z][n][k] (bf16) = scale * in[z][k][n] (f32) ----------------
__global__ void transpose_cast(const float* __restrict__ in, unsigned short* __restrict__ out,
                               int K, int N, long long inStride, long long outStride, float scale)
{
  __shared__ float tile[32][33];
  const float* src = in + (size_t)blockIdx.z * inStride;
  unsigned short* dst = out + (size_t)blockIdx.z * outStride;
  const int tx = threadIdx.x, ty = threadIdx.y;
  const int k0 = blockIdx.y*32, n0 = blockIdx.x*32;
  #pragma unroll
  for (int j = 0; j < 32; j += 8)
    tile[ty+j][tx] = src[(size_t)(k0+ty+j)*N + n0+tx];
  __syncthreads();
  #pragma unroll
  for (int j = 0; j < 32; j += 8)
    dst[(size_t)(n0+ty+j)*K + k0+tx] = f2bf(scale * tile[tx][ty+j]);
}

// ---------------- combined QKV bias: [E][2304], q-section scaled by log2(e) --------
__global__ __launch_bounds__(256) void build_qkv_bias(
    const float* __restrict__ bq, const float* __restrict__ bk, const float* __restrict__ bv,
    float* __restrict__ dst, int l)
{
  const int i = blockIdx.x*256 + threadIdx.x;   // < E_*C_
  const int g = i / C_, c = i - g*C_;
  const size_t src = ((size_t)g*L_ + l)*C_ + c;
  dst[(size_t)g*QKVS_ + c]        = LOG2E_ * bq[src];
  dst[(size_t)g*QKVS_ + C_ + c]   = bk[src];
  dst[(size_t)g*QKVS_ + 2*C_ + c] = bv[src];
}

// ---------------- V transpose per head (from fused QKV buffer) ----------------
__global__ void transpose_v_kernel(const unsigned short* __restrict__ qkv, unsigned short* __restrict__ vt)
{
  __shared__ unsigned short tile[32][33];
  const int t0 = blockIdx.x * 32, d0 = blockIdx.y * 32;
  const int z = blockIdx.z;
  const int h = z % H_, eb = z / H_;
  const int tx = threadIdx.x, ty = threadIdx.y;
  #pragma unroll
  for (int j = 0; j < 32; j += 8)
    tile[ty+j][tx] = qkv[((size_t)eb*T_ + t0+ty+j)*QKVS_ + 2*C_ + h*DH_ + d0 + tx];
  __syncthreads();
  #pragma unroll
  for (int j = 0; j < 32; j += 8)
    vt[((size_t)z*DH_ + d0+ty+j)*T_ + t0 + tx] = tile[tx][ty+j];
}

// ---------------- LN per row ----------------
__global__ __launch_bounds__(256) void ln_kernel(
    const unsigned short* __restrict__ in, unsigned short* __restrict__ out,
    const float* __restrict__ g, const float* __restrict__ b)
{
  const int row = blockIdx.x * 4 + (threadIdx.x >> 6);
  const int lane = threadIdx.x & 63;
  const int e = row >> 12;
  const unsigned short* ir = in + (size_t)row * C_;
  unsigned short* orow = out + (size_t)row * C_;
  const float* gg = g + (size_t)e * (L_*C_);
  const float* bb = b + (size_t)e * (L_*C_);
  float v[12]; float s = 0.f, s2 = 0.f;
  #pragma unroll
  for (int j = 0; j < 12; ++j) {
    float x = bf2f(ir[lane + 64*j]);
    v[j] = x; s += x; s2 += x*x;
  }
  #pragma unroll
  for (int d = 32; d; d >>= 1) { s += __shfl_xor(s, d); s2 += __shfl_xor(s2, d); }
  float mean = s * (1.f/C_);
  float var = s2 * (1.f/C_) - mean*mean;
  float rstd = rsqrtf(var + 1e-5f);
  #pragma unroll
  for (int j = 0; j < 12; ++j) {
    int c = lane + 64*j;
    orow[c] = f2bf((v[j]-mean)*rstd*gg[c] + bb[c]);
  }
}

// ---------------- gate ----------------
__global__ __launch_bounds__(256) void gate_kernel(
    const float* __restrict__ x, const float* __restrict__ gw, const float* __restrict__ gb,
    float* __restrict__ gp)
{
  const int row = blockIdx.x * 4 + (threadIdx.x >> 6);
  const int lane = threadIdx.x & 63;
  const float* xr = x + (size_t)row * C_;
  float a0=0.f, a1=0.f, a2=0.f, a3=0.f;
  for (int i = lane; i < C_; i += 64) {
    float xv = xr[i];
    float4 w = ((const float4*)gw)[i];
    a0 += xv*w.x; a1 += xv*w.y; a2 += xv*w.z; a3 += xv*w.w;
  }
  #pragma unroll
  for (int d = 32; d; d >>= 1) {
    a0 += __shfl_xor(a0,d); a1 += __shfl_xor(a1,d);
    a2 += __shfl_xor(a2,d); a3 += __shfl_xor(a3,d);
  }
  if (lane == 0) {
    a0 += gb[0]; a1 += gb[1]; a2 += gb[2]; a3 += gb[3];
    float m = fmaxf(fmaxf(a0,a1), fmaxf(a2,a3));
    float e0 = __expf(a0-m), e1 = __expf(a1-m), e2 = __expf(a2-m), e3 = __expf(a3-m);
    float inv = 1.f/(e0+e1+e2+e3);
    float4 r = {e0*inv, e1*inv, e2*inv, e3*inv};
    ((float4*)gp)[row] = r;
  }
}

// ---------------- x f32 -> bf16, replicated ----------------
__global__ __launch_bounds__(256) void cast_x_kernel(const float* __restrict__ x,
                                                     unsigned short* __restrict__ xbf)
{
  const size_t i = (size_t)blockIdx.x * 256 + threadIdx.x;
  float4 v = ((const float4*)x)[i];
  ushort4 u;
  u.x = f2bf(v.x); u.y = f2bf(v.y); u.z = f2bf(v.z); u.w = f2bf(v.w);
  #pragma unroll
  for (int e = 0; e < E_; ++e)
    ((ushort4*)(xbf + (size_t)e * ((size_t)M_*C_)))[i] = u;
}

// ---------------- combine ----------------
__global__ __launch_bounds__(256) void combine_kernel(
    const unsigned short* __restrict__ xbf, const float* __restrict__ gp, float* __restrict__ out)
{
  const size_t i = (size_t)blockIdx.x * 256 + threadIdx.x;
  const int row = (int)((i*4) / C_);
  float4 gpv = ((const float4*)gp)[row];
  const float* gpf = (const float*)&gpv;
  float r0=0.f, r1=0.f, r2=0.f, r3=0.f;
  #pragma unroll
  for (int e = 0; e < E_; ++e) {
    ushort4 u = ((const ushort4*)(xbf + (size_t)e*((size_t)M_*C_)))[i];
    float ge = gpf[e];
    r0 += ge*bf2f(u.x); r1 += ge*bf2f(u.y); r2 += ge*bf2f(u.z); r3 += ge*bf2f(u.w);
  }
  float4 res = {r0, r1, r2, r3};
  ((float4*)out)[i] = res;
}

extern "C" void kernel_launch(void* const* d_in, const int* in_sizes, int n_in,
                              void* d_out, int out_size, void* d_ws, size_t ws_size,
                              hipStream_t stream) {
  const float* x      = (const float*)d_in[0];
  const float* gate_W = (const float*)d_in[1];
  const float* gate_b = (const float*)d_in[2];
  const float* Wq = (const float*)d_in[3];
  const float* bq = (const float*)d_in[4];
  const float* Wk = (const float*)d_in[5];
  const float* bk = (const float*)d_in[6];
  const float* Wv = (const float*)d_in[7];
  const float* bv = (const float*)d_in[8];
  const float* Wo = (const float*)d_in[9];
  const float* bo = (const float*)d_in[10];
  const float* ln_g = (const float*)d_in[11];
  const float* ln_b = (const float*)d_in[12];
  const float* Wfc = (const float*)d_in[13];
  const float* bfc = (const float*)d_in[14];
  const float* Wpr = (const float*)d_in[15];
  const float* bpr = (const float*)d_in[16];
  float* out = (float*)d_out;

  const size_t CC  = (size_t)C_*C_;
  const size_t C4C = (size_t)C_*4*C_;
  const size_t MC  = (size_t)M_*C_;
  const size_t M4C = (size_t)M_*4*C_;

  char* p = (char*)d_ws;
  auto carve = [&](size_t bytes) { char* r = p; p += (bytes + 255) & ~(size_t)255; return r; };
  unsigned short* wqkvT = (unsigned short*)carve(E_*3*CC*2);  // [E][2304][768]
  unsigned short* woT   = (unsigned short*)carve(E_*CC*2);
  unsigned short* wfcT  = (unsigned short*)carve(E_*C4C*2);
  unsigned short* wprT  = (unsigned short*)carve(E_*C4C*2);
  unsigned short* xbf   = (unsigned short*)carve(E_*MC*2);
  unsigned short* r1    = (unsigned short*)carve((size_t)4*E_*MC*2);
  float* gp   = (float*)carve((size_t)M_*E_*4);
  float* bqkv = (float*)carve((size_t)E_*QKVS_*4);

  unsigned short* qkvb = r1;                          // [E][M][2304]
  unsigned short* vtb  = r1 + (size_t)3*E_*MC;        // [E*H][64][T]
  unsigned short* ob   = xbf;   // pre-LN x dead after QKV-gemm; LN writes xbf after Wo
  unsigned short* tb   = vtb;   // V^T dead after flash
  unsigned short* hb   = r1;    // qkv+vt dead by FC time

  dim3 blk256(256);
  dim3 blk512(512);
  dim3 blkT(32, 8);

  cast_x_kernel<<<dim3((unsigned)(MC/4/256)), blk256, 0, stream>>>(x, xbf);
  gate_kernel<<<dim3(M_/4), blk256, 0, stream>>>(x, gate_W, gate_b, gp);

  for (int l = 0; l < L_; ++l) {
    transpose_cast<<<dim3(24,24,E_), blkT, 0, stream>>>(Wq + l*CC, wqkvT,          C_, C_, (long long)(L_*CC), (long long)(3*CC), LOG2E_);
    transpose_cast<<<dim3(24,24,E_), blkT, 0, stream>>>(Wk + l*CC, wqkvT + CC,     C_, C_, (long long)(L_*CC), (long long)(3*CC), 1.0f);
    transpose_cast<<<dim3(24,24,E_), blkT, 0, stream>>>(Wv + l*CC, wqkvT + 2*CC,   C_, C_, (long long)(L_*CC), (long long)(3*CC), 1.0f);
    transpose_cast<<<dim3(24,24,E_), blkT, 0, stream>>>(Wo + l*CC,  woT,  C_,   C_,   (long long)(L_*CC),  (long long)CC, 1.0f);
    transpose_cast<<<dim3(96,24,E_), blkT, 0, stream>>>(Wfc + l*C4C, wfcT, C_,   4*C_, (long long)(L_*C4C), (long long)C4C, 1.0f);
    transpose_cast<<<dim3(24,96,E_), blkT, 0, stream>>>(Wpr + l*C4C, wprT, 4*C_, C_,   (long long)(L_*C4C), (long long)C4C, 1.0f);
    build_qkv_bias<<<dim3(E_*C_/256), blk256, 0, stream>>>(bq, bk, bv, bqkv, l);

    gemm256<0><<<dim3(QKVS_/256, M_/256, E_), blk512, 0, stream>>>(
        xbf, wqkvT, bqkv, qkvb, M_, QKVS_, C_, (long long)MC, (long long)(3*CC), (long long)QKVS_, (long long)M_*QKVS_, 1.0f);

    transpose_v_kernel<<<dim3(T_/32, DH_/32, E_*B_*H_), blkT, 0, stream>>>(qkvb, vtb);
    flash_attn<<<dim3(T_/128, H_, E_*B_), blk512, 0, stream>>>(qkvb, vtb, ob);

    gemm256<0><<<dim3(C_/256, M_/256, E_), blk512, 0, stream>>>(
        ob, woT, bo + l*C_, tb, M_, C_, C_, (long long)MC, (long long)CC, (long long)(L_*C_), (long long)MC, 1.0f);

    ln_kernel<<<dim3(E_*M_/4), blk256, 0, stream>>>(tb, xbf, ln_g + l*C_, ln_b + l*C_);

    gemm256<1><<<dim3(4*C_/256, M_/256, E_), blk512, 0, stream>>>(
        xbf, wfcT, bfc + l*4*C_, hb, M_, 4*C_, C_, (long long)MC, (long long)C4C, (long long)(L_*4*C_), (long long)M4C, 1.0f);
    gemm256<0><<<dim3(C_/256, M_/256, E_), blk512, 0, stream>>>(
        hb, wprT, bpr + l*C_, xbf, M_, C_, 4*C_, (long long)M4C, (long long)C4C, (long long)(L_*C_), (long long)MC, 1.0f);
  }

  combine_kernel<<<dim3((unsigned)(MC/4/256)), blk256, 0, stream>>>(xbf, gp, out);
}

// Round 21
// 908.939 us; speedup vs baseline: 5.8567x; 5.8567x over previous
//
#include <hip/hip_runtime.h>

#define B_ 4
#define T_ 1024
#define C_ 768
#define H_ 12
#define E_ 4
#define L_ 2
#define DH_ 64
#define M_ (B_*T_)   // 4096
#define QKVS_ (3*C_) // 2304, fused QKV row stride
#define LOG2E_ 1.4426950408889634f

typedef __attribute__((ext_vector_type(8))) short bf16x8;
typedef __attribute__((ext_vector_type(4))) float f32x4;

__device__ __forceinline__ unsigned short f2bf(float f) {
  unsigned int u = __float_as_uint(f);
  unsigned int r = (u + 0x7FFFu + ((u >> 16) & 1u)) >> 16;
  return (unsigned short)r;
}
__device__ __forceinline__ float bf2f(unsigned short s) {
  return __uint_as_float(((unsigned int)s) << 16);
}
// pack 2 f32 -> 2 bf16 in one u32, RNE
__device__ __forceinline__ unsigned int cvt_pk_bf16(float lo, float hi) {
  unsigned int r;
  asm("v_cvt_pk_bf16_f32 %0, %1, %2" : "=v"(r) : "v"(lo), "v"(hi));
  return r;
}
// single-instruction exp2 via COMPILER intrinsic (hazards modeled; R16 lesson)
__device__ __forceinline__ float fexp2(float x) {
#if __has_builtin(__builtin_amdgcn_exp2f)
  return __builtin_amdgcn_exp2f(x);
#else
  return exp2f(x);
#endif
}

typedef __attribute__((address_space(1))) unsigned int gu32;
typedef __attribute__((address_space(3))) unsigned int lu32;
__device__ __forceinline__ void gld_lds16(const void* g, void* l) {
  __builtin_amdgcn_global_load_lds((gu32*)g, (lu32*)l, 16, 0, 0);
}

// gelu(x) = x * sigmoid(2u)
__device__ __forceinline__ float gelu_fast(float x) {
  float u = 0.7978845608028654f * x * (1.0f + 0.044715f * x * x);
  float d = 1.0f + fexp2(-2.8853900817779268f * u);
  return x * __builtin_amdgcn_rcpf(d);
}

// ---------------- 256x256 batched GEMM, ring + FRAGMENT READ-AHEAD ------------
// R19 configuration (best measured: 905.4 us total). 4-slot ring, 1 block/CU
// (launch_bounds(512,2)); acc footprint (128 regs) makes 2 blocks/CU infeasible
// — R20's launch_bounds(512,4) spilled acc to scratch (VGPR 64, Mfma 3.5%).
#define READ_FRAGS(slot, bN, a0N, a1N)                                          \
  {                                                                             \
    _Pragma("unroll")                                                           \
    for (int nf = 0; nf < 4; ++nf)                                              \
      bN[nf] = *(const bf16x8*)&shB[slot][(brp + nf*8 + l15h)*64 + s8];         \
    _Pragma("unroll")                                                           \
    for (int i = 0; i < 4; ++i)                                                 \
      a0N[i] = *(const bf16x8*)&shA[slot][(arp + i*8 + l15h)*64 + s8];          \
    _Pragma("unroll")                                                           \
    for (int i = 0; i < 4; ++i)                                                 \
      a1N[i] = *(const bf16x8*)&shA[slot][(arp + 32 + i*8 + l15h)*64 + s8];     \
  }
#define MFMA32(bN, a0N, a1N)                                                    \
  {                                                                             \
    __builtin_amdgcn_s_setprio(1);                                              \
    _Pragma("unroll")                                                           \
    for (int i = 0; i < 4; ++i)                                                 \
      _Pragma("unroll")                                                         \
      for (int nf = 0; nf < 4; ++nf)                                            \
        acc[i][nf] = __builtin_amdgcn_mfma_f32_16x16x32_bf16(                   \
            a0N[i], bN[nf], acc[i][nf], 0, 0, 0);                               \
    _Pragma("unroll")                                                           \
    for (int i = 0; i < 4; ++i)                                                 \
      _Pragma("unroll")                                                         \
      for (int nf = 0; nf < 4; ++nf)                                            \
        acc[4+i][nf] = __builtin_amdgcn_mfma_f32_16x16x32_bf16(                 \
            a1N[i], bN[nf], acc[4+i][nf], 0, 0, 0);                             \
    __builtin_amdgcn_s_setprio(0);                                              \
  }

template <int ACT>
__global__ __launch_bounds__(512, 2) void gemm256(
    const unsigned short* __restrict__ A, const unsigned short* __restrict__ Bt,
    const float* __restrict__ bias, unsigned short* __restrict__ D,
    int M, int N, int K, long long sA, long long sB, long long sBias, long long sD,
    float bscale)
{
  __shared__ unsigned short shA[4][256*32];
  __shared__ unsigned short shB[4][256*32];
  const int tid = threadIdx.x;
  const int lane = tid & 63, wid = tid >> 6;
  const int l15 = lane & 15, lhi = lane >> 4;
  const int wm = wid >> 2, wn = wid & 3;        // 2 x 4 wave grid

  // T1: XCD-aware block swizzle (bijective: nwg % 8 == 0 for all our grids)
  const int gx = gridDim.x, gxy = gx * gridDim.y;
  const int nwg = gxy * gridDim.z;
  int flat = blockIdx.z*gxy + blockIdx.y*gx + blockIdx.x;
  flat = (flat & 7) * (nwg >> 3) + (flat >> 3);
  const int g = flat / gxy;
  const int rem = flat - g*gxy;
  const int by = rem / gx, bx = rem - by*gx;
  const int m0 = by * 256, n0 = bx * 256;

  const unsigned short* Ab = A + (size_t)g * sA;
  const unsigned short* Bb = Bt + (size_t)g * sB;
  const float* biasb = bias + (size_t)g * sBias;
  unsigned short* Db = D + (size_t)g * sD;

  f32x4 acc[8][4] = {};

  const int l15h = l15 >> 1;
  const int s8 = (((((l15 & 1) << 2) | lhi) ^ (l15h & 7)) << 3);
  const int arp = wm*64;   // + mh*32 + i*8 + l15h
  const int brp = wn*32;   // + nf*8 + l15h

  auto stageA = [&](int slot, int kh) {
    const int kb = kh << 5;
    #pragma unroll
    for (int iss = 0; iss < 2; ++iss) {
      const int c = tid + iss*512;
      const int q = c >> 3, pp = (c & 7) ^ (q & 7);
      gld_lds16(Ab + (size_t)(m0 + (q << 1) + (pp >> 2))*K + kb + ((pp & 3) << 3),
                &shA[slot][c*8]);
    }
  };
  auto stageB = [&](int slot, int kh) {
    const int kb = kh << 5;
    #pragma unroll
    for (int iss = 0; iss < 2; ++iss) {
      const int c = tid + iss*512;
      const int q = c >> 3, pp = (c & 7) ^ (q & 7);
      gld_lds16(Bb + (size_t)(n0 + (q << 1) + (pp >> 2))*K + kb + ((pp & 3) << 3),
                &shB[slot][c*8]);
    }
  };

  const int nkt = K >> 6;
  const int nkh = nkt << 1;      // even; >= 6 for all our shapes

  // prologue: stage kh 0,1,2; vmcnt(4) confirms kh0,kh1 (kh2 in flight)
  stageA(0, 0); stageB(0, 0);
  stageA(1, 1); stageB(1, 1);
  stageA(2, 2); stageB(2, 2);
  asm volatile("s_waitcnt vmcnt(4)" ::: "memory");
  __builtin_amdgcn_s_barrier();

  bf16x8 bA[4], aA0[4], aA1[4], bB[4], aB0[4], aB1[4];
  READ_FRAGS(0, bA, aA0, aA1);

  for (int mt = 0; mt < nkh; mt += 2) {
    // ---- phase A: kh = mt (frags in A-set); read-ahead kh mt+1 ----
    READ_FRAGS((mt + 1) & 3, bB, aB0, aB1);           // slot mt+1 confirmed
    {
      const int mst = mt + 3;
      if (mst < nkh) { stageA(mst & 3, mst); stageB(mst & 3, mst); }
    }
    MFMA32(bA, aA0, aA1);
    if (mt + 3 < nkh) asm volatile("s_waitcnt vmcnt(4)" ::: "memory");  // confirms mt+2
    else              asm volatile("s_waitcnt vmcnt(0)" ::: "memory");
    __builtin_amdgcn_s_barrier();
    // ---- phase B: kh = mt+1 (frags in B-set); read-ahead kh mt+2 ----
    if (mt + 2 < nkh) READ_FRAGS((mt + 2) & 3, bA, aA0, aA1);
    {
      const int mst = mt + 4;
      if (mst < nkh) { stageA(mst & 3, mst); stageB(mst & 3, mst); }
    }
    MFMA32(bB, aB0, aB1);
    if (mt + 2 < nkh) {
      if (mt + 4 < nkh) asm volatile("s_waitcnt vmcnt(4)" ::: "memory");
      else              asm volatile("s_waitcnt vmcnt(0)" ::: "memory");
      __builtin_amdgcn_s_barrier();
    }
  }

  // ---- LDS-staged coalesced C-write (fully unrolled: static acc indexing) ----
  unsigned short* cbuf = (unsigned short*)&shA[0][0];
  const int lr = tid >> 4, ckk = tid & 15;
  const int growb = m0 + ((lr >> 4) ? 128 : 0) + (lr & 15);
  #pragma unroll
  for (int mf = 0; mf < 8; ++mf) {
    __builtin_amdgcn_s_barrier();
    #pragma unroll
    for (int nf = 0; nf < 4; ++nf) {
      const int col = wn*64 + nf*16 + l15;
      const float bv = bscale * biasb[n0 + col];
      #pragma unroll
      for (int r = 0; r < 4; ++r) {
        float v = acc[mf][nf][r] + bv;
        if (ACT == 1) v = gelu_fast(v);
        cbuf[(wm*16 + lhi*4 + r)*264 + col] = f2bf(v);
      }
    }
    __builtin_amdgcn_s_barrier();
    const size_t growN = (size_t)(growb + mf*16) * N + n0;
    #pragma unroll
    for (int cc2 = 0; cc2 < 2; ++cc2) {
      const int c = ckk + cc2*16;
      uint4 v = *(const uint4*)&cbuf[lr*264 + c*8];
      *(uint4*)&Db[growN + c*8] = v;
    }
  }
}

// ---------------- flash attention: QBLK=128 (8 waves), swapped-QK^T, no-max ----
__global__ __launch_bounds__(512) void flash_attn(
    const unsigned short* __restrict__ qkv, const unsigned short* __restrict__ vt,
    unsigned short* __restrict__ o)
{
  __shared__ unsigned short shK[2][64*64];
  __shared__ unsigned short shV[2][64*64];   // V^T tile: [d][t]
  __shared__ unsigned short shP[8][16*64];
  const int tid = threadIdx.x;
  const int wid = tid >> 6, lane = tid & 63;
  const int l15 = lane & 15, lhi = lane >> 4;
  const int qt = blockIdx.x, h = blockIdx.y, eb = blockIdx.z;

  const unsigned short* qrow = qkv + ((size_t)eb*T_ + qt*128 + wid*16 + l15) * QKVS_ + h*DH_;
  bf16x8 aq0 = *(const bf16x8*)(qrow + lhi*8);
  bf16x8 aq1 = *(const bf16x8*)(qrow + 32 + lhi*8);

  f32x4 oacc[4] = {};
  float lpart = 0.f;   // per-lane partial denominator, qrow = l15

  const int krow = tid >> 3;                               // 0..63 (512 threads)
  const int swzsrc = (((tid & 7) ^ (krow & 7)) << 3);
  const unsigned short* kbase = qkv + (size_t)eb*T_*QKVS_ + C_ + h*DH_;
  const unsigned short* vbase = vt + ((size_t)eb*H_ + h)*DH_*T_;

  auto stage = [&](int buf, int kt) {
    gld_lds16(kbase + (size_t)(kt*64 + krow)*QKVS_ + swzsrc, &shK[buf][tid*8]);
    gld_lds16(vbase + (size_t)krow*T_ + kt*64 + swzsrc,      &shV[buf][tid*8]);
  };

  stage(0, 0);
  __syncthreads();
  int cur = 0;
  const int swzr = l15 & 7;
  const int c0 = (lhi ^ swzr) << 3;
  const int c1 = ((4 + lhi) ^ swzr) << 3;
  const int pwbase = l15*64 + ((lhi & 1) << 2);
  const int pwh = lhi >> 1;

  for (int kt = 0; kt < T_/64; ++kt) {
    if (kt + 1 < T_/64) stage(cur ^ 1, kt + 1);

    f32x4 s[4];
    #pragma unroll
    for (int kb = 0; kb < 4; ++kb) {
      const int row = (kb*16 + l15)*64;
      bf16x8 bk0 = *(const bf16x8*)&shK[cur][row + c0];
      bf16x8 bk1 = *(const bf16x8*)&shK[cur][row + c1];
      f32x4 z = {};
      z = __builtin_amdgcn_mfma_f32_16x16x32_bf16(bk0, aq0, z, 0, 0, 0);       // swapped
      s[kb] = __builtin_amdgcn_mfma_f32_16x16x32_bf16(bk1, aq1, z, 0, 0, 0);
    }
    unsigned int pk0[4], pk1[4];
    #pragma unroll
    for (int kb = 0; kb < 4; ++kb) {
      #pragma unroll
      for (int r = 0; r < 4; ++r) {
        float pv = fexp2(s[kb][r]);
        s[kb][r] = pv;
        lpart += pv;
      }
      pk0[kb] = cvt_pk_bf16(s[kb][0], s[kb][1]);
      pk1[kb] = cvt_pk_bf16(s[kb][2], s[kb][3]);
    }
    #pragma unroll
    for (int kb = 0; kb < 4; ++kb) {
      const int chunk = (2*kb + pwh) ^ swzr;
      uint2 w = {pk0[kb], pk1[kb]};
      *(uint2*)&shP[wid][pwbase + chunk*8] = w;
    }
    bf16x8 pa0 = *(const bf16x8*)&shP[wid][l15*64 + c0];
    bf16x8 pa1 = *(const bf16x8*)&shP[wid][l15*64 + c1];
    #pragma unroll
    for (int n = 0; n < 4; ++n) {
      const int row = (n*16 + l15)*64;
      bf16x8 bv0 = *(const bf16x8*)&shV[cur][row + c0];
      bf16x8 bv1 = *(const bf16x8*)&shV[cur][row + c1];
      oacc[n] = __builtin_amdgcn_mfma_f32_16x16x32_bf16(pa0, bv0, oacc[n], 0, 0, 0);
      oacc[n] = __builtin_amdgcn_mfma_f32_16x16x32_bf16(pa1, bv1, oacc[n], 0, 0, 0);
    }
    __syncthreads();
    cur ^= 1;
  }
  lpart += __shfl_xor(lpart, 16);
  lpart += __shfl_xor(lpart, 32);
  float li[4];
  #pragma unroll
  for (int r = 0; r < 4; ++r) li[r] = __shfl(lpart, lhi*4 + r);
  #pragma unroll
  for (int n = 0; n < 4; ++n)
    #pragma unroll
    for (int r = 0; r < 4; ++r) {
      float v = oacc[n][r] / li[r];
      o[((size_t)eb*T_ + qt*128 + wid*16 + lhi*4 + r) * C_ + h*DH_ + n*16 + l15] = f2bf(v);
    }
}

// ---------------- transpose+cast: out[z][n][k] (bf16) = scale * in[z][k][n] (f32) ----------------
__global__ void transpose_cast(const float* __restrict__ in, unsigned short* __restrict__ out,
                               int K, int N, long long inStride, long long outStride, float scale)
{
  __shared__ float tile[32][33];
  const float* src = in + (size_t)blockIdx.z * inStride;
  unsigned short* dst = out + (size_t)blockIdx.z * outStride;
  const int tx = threadIdx.x, ty = threadIdx.y;
  const int k0 = blockIdx.y*32, n0 = blockIdx.x*32;
  #pragma unroll
  for (int j = 0; j < 32; j += 8)
    tile[ty+j][tx] = src[(size_t)(k0+ty+j)*N + n0+tx];
  __syncthreads();
  #pragma unroll
  for (int j = 0; j < 32; j += 8)
    dst[(size_t)(n0+ty+j)*K + k0+tx] = f2bf(scale * tile[tx][ty+j]);
}

// ---------------- combined QKV bias: [E][2304], q-section scaled by log2(e) --------
__global__ __launch_bounds__(256) void build_qkv_bias(
    const float* __restrict__ bq, const float* __restrict__ bk, const float* __restrict__ bv,
    float* __restrict__ dst, int l)
{
  const int i = blockIdx.x*256 + threadIdx.x;   // < E_*C_
  const int g = i / C_, c = i - g*C_;
  const size_t src = ((size_t)g*L_ + l)*C_ + c;
  dst[(size_t)g*QKVS_ + c]        = LOG2E_ * bq[src];
  dst[(size_t)g*QKVS_ + C_ + c]   = bk[src];
  dst[(size_t)g*QKVS_ + 2*C_ + c] = bv[src];
}

// ---------------- V transpose per head (from fused QKV buffer) ----------------
__global__ void transpose_v_kernel(const unsigned short* __restrict__ qkv, unsigned short* __restrict__ vt)
{
  __shared__ unsigned short tile[32][33];
  const int t0 = blockIdx.x * 32, d0 = blockIdx.y * 32;
  const int z = blockIdx.z;
  const int h = z % H_, eb = z / H_;
  const int tx = threadIdx.x, ty = threadIdx.y;
  #pragma unroll
  for (int j = 0; j < 32; j += 8)
    tile[ty+j][tx] = qkv[((size_t)eb*T_ + t0+ty+j)*QKVS_ + 2*C_ + h*DH_ + d0 + tx];
  __syncthreads();
  #pragma unroll
  for (int j = 0; j < 32; j += 8)
    vt[((size_t)z*DH_ + d0+ty+j)*T_ + t0 + tx] = tile[tx][ty+j];
}

// ---------------- LN per row ----------------
__global__ __launch_bounds__(256) void ln_kernel(
    const unsigned short* __restrict__ in, unsigned short* __restrict__ out,
    const float* __restrict__ g, const float* __restrict__ b)
{
  const int row = blockIdx.x * 4 + (threadIdx.x >> 6);
  const int lane = threadIdx.x & 63;
  const int e = row >> 12;
  const unsigned short* ir = in + (size_t)row * C_;
  unsigned short* orow = out + (size_t)row * C_;
  const float* gg = g + (size_t)e * (L_*C_);
  const float* bb = b + (size_t)e * (L_*C_);
  float v[12]; float s = 0.f, s2 = 0.f;
  #pragma unroll
  for (int j = 0; j < 12; ++j) {
    float x = bf2f(ir[lane + 64*j]);
    v[j] = x; s += x; s2 += x*x;
  }
  #pragma unroll
  for (int d = 32; d; d >>= 1) { s += __shfl_xor(s, d); s2 += __shfl_xor(s2, d); }
  float mean = s * (1.f/C_);
  float var = s2 * (1.f/C_) - mean*mean;
  float rstd = rsqrtf(var + 1e-5f);
  #pragma unroll
  for (int j = 0; j < 12; ++j) {
    int c = lane + 64*j;
    orow[c] = f2bf((v[j]-mean)*rstd*gg[c] + bb[c]);
  }
}

// ---------------- gate ----------------
__global__ __launch_bounds__(256) void gate_kernel(
    const float* __restrict__ x, const float* __restrict__ gw, const float* __restrict__ gb,
    float* __restrict__ gp)
{
  const int row = blockIdx.x * 4 + (threadIdx.x >> 6);
  const int lane = threadIdx.x & 63;
  const float* xr = x + (size_t)row * C_;
  float a0=0.f, a1=0.f, a2=0.f, a3=0.f;
  for (int i = lane; i < C_; i += 64) {
    float xv = xr[i];
    float4 w = ((const float4*)gw)[i];
    a0 += xv*w.x; a1 += xv*w.y; a2 += xv*w.z; a3 += xv*w.w;
  }
  #pragma unroll
  for (int d = 32; d; d >>= 1) {
    a0 += __shfl_xor(a0,d); a1 += __shfl_xor(a1,d);
    a2 += __shfl_xor(a2,d); a3 += __shfl_xor(a3,d);
  }
  if (lane == 0) {
    a0 += gb[0]; a1 += gb[1]; a2 += gb[2]; a3 += gb[3];
    float m = fmaxf(fmaxf(a0,a1), fmaxf(a2,a3));
    float e0 = __expf(a0-m), e1 = __expf(a1-m), e2 = __expf(a2-m), e3 = __expf(a3-m);
    float inv = 1.f/(e0+e1+e2+e3);
    float4 r = {e0*inv, e1*inv, e2*inv, e3*inv};
    ((float4*)gp)[row] = r;
  }
}

// ---------------- x f32 -> bf16, replicated ----------------
__global__ __launch_bounds__(256) void cast_x_kernel(const float* __restrict__ x,
                                                     unsigned short* __restrict__ xbf)
{
  const size_t i = (size_t)blockIdx.x * 256 + threadIdx.x;
  float4 v = ((const float4*)x)[i];
  ushort4 u;
  u.x = f2bf(v.x); u.y = f2bf(v.y); u.z = f2bf(v.z); u.w = f2bf(v.w);
  #pragma unroll
  for (int e = 0; e < E_; ++e)
    ((ushort4*)(xbf + (size_t)e * ((size_t)M_*C_)))[i] = u;
}

// ---------------- combine ----------------
__global__ __launch_bounds__(256) void combine_kernel(
    const unsigned short* __restrict__ xbf, const float* __restrict__ gp, float* __restrict__ out)
{
  const size_t i = (size_t)blockIdx.x * 256 + threadIdx.x;
  const int row = (int)((i*4) / C_);
  float4 gpv = ((const float4*)gp)[row];
  const float* gpf = (const float*)&gpv;
  float r0=0.f, r1=0.f, r2=0.f, r3=0.f;
  #pragma unroll
  for (int e = 0; e < E_; ++e) {
    ushort4 u = ((const ushort4*)(xbf + (size_t)e*((size_t)M_*C_)))[i];
    float ge = gpf[e];
    r0 += ge*bf2f(u.x); r1 += ge*bf2f(u.y); r2 += ge*bf2f(u.z); r3 += ge*bf2f(u.w);
  }
  float4 res = {r0, r1, r2, r3};
  ((float4*)out)[i] = res;
}

extern "C" void kernel_launch(void* const* d_in, const int* in_sizes, int n_in,
                              void* d_out, int out_size, void* d_ws, size_t ws_size,
                              hipStream_t stream) {
  const float* x      = (const float*)d_in[0];
  const float* gate_W = (const float*)d_in[1];
  const float* gate_b = (const float*)d_in[2];
  const float* Wq = (const float*)d_in[3];
  const float* bq = (const float*)d_in[4];
  const float* Wk = (const float*)d_in[5];
  const float* bk = (const float*)d_in[6];
  const float* Wv = (const float*)d_in[7];
  const float* bv = (const float*)d_in[8];
  const float* Wo = (const float*)d_in[9];
  const float* bo = (const float*)d_in[10];
  const float* ln_g = (const float*)d_in[11];
  const float* ln_b = (const float*)d_in[12];
  const float* Wfc = (const float*)d_in[13];
  const float* bfc = (const float*)d_in[14];
  const float* Wpr = (const float*)d_in[15];
  const float* bpr = (const float*)d_in[16];
  float* out = (float*)d_out;

  const size_t CC  = (size_t)C_*C_;
  const size_t C4C = (size_t)C_*4*C_;
  const size_t MC  = (size_t)M_*C_;
  const size_t M4C = (size_t)M_*4*C_;

  char* p = (char*)d_ws;
  auto carve = [&](size_t bytes) { char* r = p; p += (bytes + 255) & ~(size_t)255; return r; };
  unsigned short* wqkvT = (unsigned short*)carve(E_*3*CC*2);  // [E][2304][768]
  unsigned short* woT   = (unsigned short*)carve(E_*CC*2);
  unsigned short* wfcT  = (unsigned short*)carve(E_*C4C*2);
  unsigned short* wprT  = (unsigned short*)carve(E_*C4C*2);
  unsigned short* xbf   = (unsigned short*)carve(E_*MC*2);
  unsigned short* r1    = (unsigned short*)carve((size_t)4*E_*MC*2);
  float* gp   = (float*)carve((size_t)M_*E_*4);
  float* bqkv = (float*)carve((size_t)E_*QKVS_*4);

  unsigned short* qkvb = r1;                          // [E][M][2304]
  unsigned short* vtb  = r1 + (size_t)3*E_*MC;        // [E*H][64][T]
  unsigned short* ob   = xbf;   // pre-LN x dead after QKV-gemm; LN writes xbf after Wo
  unsigned short* tb   = vtb;   // V^T dead after flash
  unsigned short* hb   = r1;    // qkv+vt dead by FC time

  dim3 blk256(256);
  dim3 blk512(512);
  dim3 blkT(32, 8);

  cast_x_kernel<<<dim3((unsigned)(MC/4/256)), blk256, 0, stream>>>(x, xbf);
  gate_kernel<<<dim3(M_/4), blk256, 0, stream>>>(x, gate_W, gate_b, gp);

  for (int l = 0; l < L_; ++l) {
    transpose_cast<<<dim3(24,24,E_), blkT, 0, stream>>>(Wq + l*CC, wqkvT,          C_, C_, (long long)(L_*CC), (long long)(3*CC), LOG2E_);
    transpose_cast<<<dim3(24,24,E_), blkT, 0, stream>>>(Wk + l*CC, wqkvT + CC,     C_, C_, (long long)(L_*CC), (long long)(3*CC), 1.0f);
    transpose_cast<<<dim3(24,24,E_), blkT, 0, stream>>>(Wv + l*CC, wqkvT + 2*CC,   C_, C_, (long long)(L_*CC), (long long)(3*CC), 1.0f);
    transpose_cast<<<dim3(24,24,E_), blkT, 0, stream>>>(Wo + l*CC,  woT,  C_,   C_,   (long long)(L_*CC),  (long long)CC, 1.0f);
    transpose_cast<<<dim3(96,24,E_), blkT, 0, stream>>>(Wfc + l*C4C, wfcT, C_,   4*C_, (long long)(L_*C4C), (long long)C4C, 1.0f);
    transpose_cast<<<dim3(24,96,E_), blkT, 0, stream>>>(Wpr + l*C4C, wprT, 4*C_, C_,   (long long)(L_*C4C), (long long)C4C, 1.0f);
    build_qkv_bias<<<dim3(E_*C_/256), blk256, 0, stream>>>(bq, bk, bv, bqkv, l);

    gemm256<0><<<dim3(QKVS_/256, M_/256, E_), blk512, 0, stream>>>(
        xbf, wqkvT, bqkv, qkvb, M_, QKVS_, C_, (long long)MC, (long long)(3*CC), (long long)QKVS_, (long long)M_*QKVS_, 1.0f);

    transpose_v_kernel<<<dim3(T_/32, DH_/32, E_*B_*H_), blkT, 0, stream>>>(qkvb, vtb);
    flash_attn<<<dim3(T_/128, H_, E_*B_), blk512, 0, stream>>>(qkvb, vtb, ob);

    gemm256<0><<<dim3(C_/256, M_/256, E_), blk512, 0, stream>>>(
        ob, woT, bo + l*C_, tb, M_, C_, C_, (long long)MC, (long long)CC, (long long)(L_*C_), (long long)MC, 1.0f);

    ln_kernel<<<dim3(E_*M_/4), blk256, 0, stream>>>(tb, xbf, ln_g + l*C_, ln_b + l*C_);

    gemm256<1><<<dim3(4*C_/256, M_/256, E_), blk512, 0, stream>>>(
        xbf, wfcT, bfc + l*4*C_, hb, M_, 4*C_, C_, (long long)MC, (long long)C4C, (long long)(L_*4*C_), (long long)M4C, 1.0f);
    gemm256<0><<<dim3(C_/256, M_/256, E_), blk512, 0, stream>>>(
        hb, wprT, bpr + l*C_, xbf, M_, C_, 4*C_, (long long)M4C, (long long)C4C, (long long)(L_*C_), (long long)MC, 1.0f);
  }

  combine_kernel<<<dim3((unsigned)(MC/4/256)), blk256, 0, stream>>>(xbf, gp, out);
}